// Round 1
// baseline (1098.469 us; speedup 1.0000x reference)
//
#include <hip/hip_runtime.h>

#define N 512
#define L 8192
#define BATCH 64

// ---------------------------------------------------------------------------
// ws layout (floats):
// [0]           delta
// [64]          At   (N*N)   A transposed (At[i][j] = A[j][i])
// [64+N*N]      Ad   (N*N)   discretized A (lower tri, zeros above)
// [64+2*N*N]    Pa   (N*N)   squaring scratch (alternates with Ad buffer)
// then          V    (128*N) V[r][:] = Ad^r Bd   (row 0 = Bd)
// then          W    (64*N)  W[q][:] = C Ad^(128q)
// then          kvec (L)
// total ~3.6 MB
// ---------------------------------------------------------------------------

__global__ __launch_bounds__(256) void k_prep(const float* __restrict__ A,
                                              const float* __restrict__ logd,
                                              const float* __restrict__ C,
                                              float* __restrict__ At,
                                              float* __restrict__ wdelta,
                                              float* __restrict__ W) {
  __shared__ float tile[32][33];
  int tx = threadIdx.x, ty = threadIdx.y;
  int x0 = blockIdx.x * 32, y0 = blockIdx.y * 32;
#pragma unroll
  for (int m = 0; m < 4; ++m)
    tile[ty + 8 * m][tx] = A[(size_t)(y0 + ty + 8 * m) * N + x0 + tx];
  __syncthreads();
#pragma unroll
  for (int m = 0; m < 4; ++m)
    At[(size_t)(x0 + ty + 8 * m) * N + y0 + tx] = tile[tx][ty + 8 * m];
  if (blockIdx.x == 0 && blockIdx.y == 0 && tx == 0 && ty == 0) {
    float ld = logd[0];
    ld = fminf(fmaxf(ld, logf(1e-3f)), logf(0.1f));
    wdelta[0] = expf(ld);
  }
  if (blockIdx.y == 0 && ty == 0)
    W[blockIdx.x * 32 + tx] = C[blockIdx.x * 32 + tx];
}

// Forward substitution: A1 x = rhs, A1 = I - (delta/2) A  (lower triangular).
// Block j<512: rhs = column j of A2 = I + (delta/2)A  -> Ad column j.
// Block 512:  rhs = delta*Bm -> Bd (stored as V row 0).
// x kept in registers (2 rows/thread); only the pivot value goes through LDS.
__global__ __launch_bounds__(256) void k_solve(const float* __restrict__ At,
                                               const float* __restrict__ wdelta,
                                               const float* __restrict__ Bm,
                                               float* __restrict__ Ad,
                                               float* __restrict__ V) {
  int j = blockIdx.x;  // 0..511: Ad column; 512: Bd
  int tid = threadIdx.x;
  int r0 = tid, r1 = tid + 256;
  float delta = wdelta[0];
  float half = 0.5f * delta;
  __shared__ float xsh[2];
  int kstart;
  float x0, x1;
  if (j < N) {
    kstart = j;
    x0 = (r0 == j) ? 1.0f + half * At[(size_t)j * N + j]
       : (r0 > j ? half * At[(size_t)j * N + r0] : 0.0f);
    x1 = (r1 == j) ? 1.0f + half * At[(size_t)j * N + j]
       : (r1 > j ? half * At[(size_t)j * N + r1] : 0.0f);
  } else {
    kstart = 0;
    x0 = delta * Bm[r0];
    x1 = delta * Bm[r1];
  }
  float dinv0 = 1.0f / (1.0f - half * At[(size_t)r0 * N + r0]);
  float dinv1 = 1.0f / (1.0f - half * At[(size_t)r1 * N + r1]);
  if (r0 == kstart) { x0 *= dinv0; xsh[kstart & 1] = x0; }
  if (r1 == kstart) { x1 *= dinv1; xsh[kstart & 1] = x1; }
  float a0 = At[(size_t)kstart * N + r0];
  float a1 = At[(size_t)kstart * N + r1];
  __syncthreads();
  for (int kk = kstart; kk < N; ++kk) {
    float xk = xsh[kk & 1];
    float an0 = 0.0f, an1 = 0.0f;
    if (kk + 1 < N) {  // prefetch next At row (hides part of L2 latency)
      an0 = At[(size_t)(kk + 1) * N + r0];
      an1 = At[(size_t)(kk + 1) * N + r1];
    }
    if (r0 > kk) x0 += half * a0 * xk;   // x -= A1[i][kk]*xk, A1 off-diag = -half*A
    if (r1 > kk) x1 += half * a1 * xk;
    if (r0 == kk + 1) { x0 *= dinv0; xsh[(kk + 1) & 1] = x0; }
    if (r1 == kk + 1) { x1 *= dinv1; xsh[(kk + 1) & 1] = x1; }
    a0 = an0; a1 = an1;
    __syncthreads();
  }
  if (j < N) {
    Ad[(size_t)r0 * N + j] = (r0 >= j) ? x0 : 0.0f;
    Ad[(size_t)r1 * N + j] = (r1 >= j) ? x1 : 0.0f;
  } else {
    V[r0] = x0;
    V[r1] = x1;
  }
}

// Q = P*P for 512x512 lower-triangular P (writes zeros above diagonal).
__global__ __launch_bounds__(256) void k_matsq(const float* __restrict__ P,
                                               float* __restrict__ Q) {
  int bi = blockIdx.y, bj = blockIdx.x;
  int tid = threadIdx.x;
  int tx = tid & 31, ty = tid >> 5;
  if (bi < bj) {
#pragma unroll
    for (int m = 0; m < 4; ++m)
      Q[(size_t)(bi * 32 + ty + 8 * m) * N + bj * 32 + tx] = 0.0f;
    return;
  }
  __shared__ float As[32][33], Bs[32][33];
  float acc[4] = {0.0f, 0.0f, 0.0f, 0.0f};
  for (int kb = bj; kb <= bi; ++kb) {
#pragma unroll
    for (int m = 0; m < 4; ++m) {
      As[ty + 8 * m][tx] = P[(size_t)(bi * 32 + ty + 8 * m) * N + kb * 32 + tx];
      Bs[ty + 8 * m][tx] = P[(size_t)(kb * 32 + ty + 8 * m) * N + bj * 32 + tx];
    }
    __syncthreads();
#pragma unroll
    for (int kk = 0; kk < 32; ++kk) {
      float b = Bs[kk][tx];
#pragma unroll
      for (int m = 0; m < 4; ++m) acc[m] += As[ty + 8 * m][kk] * b;
    }
    __syncthreads();
  }
#pragma unroll
  for (int m = 0; m < 4; ++m)
    Q[(size_t)(bi * 32 + ty + 8 * m) * N + bj * 32 + tx] = acc[m];
}

// V[base+c][:] = P * V[c][:]  for c in [0, base)   (P = Ad^base)
__global__ __launch_bounds__(256) void k_vstep(const float* __restrict__ P,
                                               float* __restrict__ V,
                                               int base) {
  __shared__ float vc[N];
  int c = blockIdx.x;
  int tid = threadIdx.x;
  vc[tid] = V[(size_t)c * N + tid];
  vc[tid + 256] = V[(size_t)c * N + tid + 256];
  __syncthreads();
  int row = blockIdx.y * 256 + tid;
  const float* Pr = P + (size_t)row * N;
  float acc = 0.0f;
  for (int k = 0; k <= row; ++k) acc += Pr[k] * vc[k];  // P lower-tri
  V[(size_t)(base + c) * N + row] = acc;
}

// W[base+q][:] = W[q][:] * P    (P = (Ad^128)^base)
__global__ __launch_bounds__(256) void k_wstep(const float* __restrict__ P,
                                               float* __restrict__ W,
                                               int base) {
  __shared__ float wq[N];
  int q = blockIdx.x;
  int tid = threadIdx.x;
  wq[tid] = W[(size_t)q * N + tid];
  wq[tid + 256] = W[(size_t)q * N + tid + 256];
  __syncthreads();
  int c = blockIdx.y * 256 + tid;
  float acc = 0.0f;
  for (int k = 0; k < N; ++k) acc += wq[k] * P[(size_t)k * N + c];
  W[(size_t)(base + q) * N + c] = acc;
}

// kvec[q*128+r] = dot(W[q], V[r])
__global__ __launch_bounds__(128) void k_kfinal(const float* __restrict__ W,
                                                const float* __restrict__ V,
                                                float* __restrict__ kvec) {
  __shared__ float wq[N];
  int q = blockIdx.x;
  int tid = threadIdx.x;
  for (int i = tid; i < N; i += 128) wq[i] = W[(size_t)q * N + i];
  __syncthreads();
  const float* Vr = V + (size_t)tid * N;
  float acc = 0.0f;
  for (int n = 0; n < N; ++n) acc += wq[n] * Vr[n];
  kvec[q * 128 + tid] = acc;
}

// y[b,t] = D*X[b,t] + sum_{s<=t} kvec[s] * X[b,t-s]
// Block: batch b, 1024 outputs (t0..t0+1023), 4 per thread (stride 256).
__global__ __launch_bounds__(256) void k_conv(const float* __restrict__ X,
                                              const float* __restrict__ kvec,
                                              const float* __restrict__ Dp,
                                              float* __restrict__ Y) {
  __shared__ float ks[256];
  __shared__ float xs[1280];
  int tid = threadIdx.x;
  int b = blockIdx.y;
  int t0 = blockIdx.x * 1024;
  const float* Xb = X + (size_t)b * L;
  float acc0 = 0.f, acc1 = 0.f, acc2 = 0.f, acc3 = 0.f;
  int smax = t0 + 768;
  for (int s0 = 0; s0 <= smax; s0 += 256) {
    ks[tid] = kvec[s0 + tid];
    int ulo = t0 - s0 - 255;
#pragma unroll
    for (int i = tid; i < 1280; i += 256) {
      int u = ulo + i;
      xs[i] = (u >= 0 && u < L) ? Xb[u] : 0.0f;
    }
    __syncthreads();
    int off = s0 - t0;
    if (off < 0) {
#pragma unroll 4
      for (int ds = 0; ds < 256; ++ds) {
        float kvv = ks[ds];
        int bidx = tid + 255 - ds;
        acc0 += kvv * xs[bidx];
        acc1 += kvv * xs[bidx + 256];
        acc2 += kvv * xs[bidx + 512];
        acc3 += kvv * xs[bidx + 768];
      }
    } else {
      int d = off >> 8;  // which rr is on the causal diagonal
      for (int ds = 0; ds < 256; ++ds) {
        float kvv = ks[ds];
        int bidx = tid + 255 - ds;
        bool p = (ds <= tid);
        if (d == 0) {
          if (p) acc0 += kvv * xs[bidx];
          acc1 += kvv * xs[bidx + 256];
          acc2 += kvv * xs[bidx + 512];
          acc3 += kvv * xs[bidx + 768];
        } else if (d == 1) {
          if (p) acc1 += kvv * xs[bidx + 256];
          acc2 += kvv * xs[bidx + 512];
          acc3 += kvv * xs[bidx + 768];
        } else if (d == 2) {
          if (p) acc2 += kvv * xs[bidx + 512];
          acc3 += kvv * xs[bidx + 768];
        } else {
          if (p) acc3 += kvv * xs[bidx + 768];
        }
      }
    }
    __syncthreads();
  }
  float D0 = Dp[0];
  size_t base = (size_t)b * L + t0 + tid;
  Y[base]       = acc0 + D0 * Xb[t0 + tid];
  Y[base + 256] = acc1 + D0 * Xb[t0 + tid + 256];
  Y[base + 512] = acc2 + D0 * Xb[t0 + tid + 512];
  Y[base + 768] = acc3 + D0 * Xb[t0 + tid + 768];
}

extern "C" void kernel_launch(void* const* d_in, const int* in_sizes, int n_in,
                              void* d_out, int out_size, void* d_ws, size_t ws_size,
                              hipStream_t stream) {
  const float* X  = (const float*)d_in[0];
  const float* A  = (const float*)d_in[1];
  const float* Bm = (const float*)d_in[2];
  const float* C  = (const float*)d_in[3];
  const float* D  = (const float*)d_in[4];
  const float* ld = (const float*)d_in[5];
  float* Y = (float*)d_out;

  float* ws = (float*)d_ws;
  float* wdelta = ws;
  float* At = ws + 64;
  float* Ad = At + N * N;
  float* Pa = Ad + N * N;
  float* V  = Pa + N * N;      // 128 rows of N  (row 0 = Bd)
  float* W  = V + 128 * N;     // 64 rows of N
  float* kv = W + 64 * N;      // L

  k_prep<<<dim3(16, 16), dim3(32, 8), 0, stream>>>(A, ld, C, At, wdelta, W);
  k_solve<<<513, 256, 0, stream>>>(At, wdelta, Bm, Ad, V);

  float* Pcur = Ad;   // currently Ad^1
  float* Poth = Pa;
  for (int j = 0; j < 7; ++j) {   // V doubling to 128 cols; P -> Ad^128
    k_vstep<<<dim3(1 << j, 2), 256, 0, stream>>>(Pcur, V, 1 << j);
    k_matsq<<<dim3(16, 16), 256, 0, stream>>>(Pcur, Poth);
    float* t = Pcur; Pcur = Poth; Poth = t;
  }
  for (int i = 0; i < 6; ++i) {   // W doubling to 64 rows with powers of Ad^128
    k_wstep<<<dim3(1 << i, 2), 256, 0, stream>>>(Pcur, W, 1 << i);
    if (i < 5) {
      k_matsq<<<dim3(16, 16), 256, 0, stream>>>(Pcur, Poth);
      float* t = Pcur; Pcur = Poth; Poth = t;
    }
  }
  k_kfinal<<<64, 128, 0, stream>>>(W, V, kv);
  k_conv<<<dim3(8, BATCH), 256, 0, stream>>>(X, kv, D, Y);
}

// Round 2
// 676.656 us; speedup vs baseline: 1.6234x; 1.6234x over previous
//
#include <hip/hip_runtime.h>

#define N 512
#define L 8192
#define BATCH 64

typedef __attribute__((ext_vector_type(8))) short short8;
typedef __attribute__((ext_vector_type(4))) float f32x4;
typedef __attribute__((ext_vector_type(4))) unsigned int uint4v;

__device__ __forceinline__ unsigned short f2bf(float x) {
  union { float f; unsigned int u; } c; c.f = x;
  unsigned int u = c.u;
  u += 0x7FFFu + ((u >> 16) & 1u);   // round-to-nearest-even
  return (unsigned short)(u >> 16);
}
__device__ __forceinline__ unsigned int pack2(unsigned short a, unsigned short b) {
  return (unsigned int)a | ((unsigned int)b << 16);
}

// ---------------------------------------------------------------------------
// ws layout (floats):
// [0]       delta
// [64]      At   (N*N)  A^T; dead after k_solve  -> reused as Atab (bf16 A-frags, 1MB)
// +N*N      Ad   (N*N)  squaring buffer          -> reused as Btab (bf16 B-frags, 0.5MB)
// +N*N      Pa   (N*N)  squaring scratch
// then      V    (128*N), W (64*N), kvec (L)
// ---------------------------------------------------------------------------

__global__ __launch_bounds__(256) void k_prep(const float* __restrict__ A,
                                              const float* __restrict__ logd,
                                              const float* __restrict__ C,
                                              float* __restrict__ At,
                                              float* __restrict__ wdelta,
                                              float* __restrict__ W) {
  __shared__ float tile[32][33];
  int tx = threadIdx.x, ty = threadIdx.y;
  int x0 = blockIdx.x * 32, y0 = blockIdx.y * 32;
#pragma unroll
  for (int m = 0; m < 4; ++m)
    tile[ty + 8 * m][tx] = A[(size_t)(y0 + ty + 8 * m) * N + x0 + tx];
  __syncthreads();
#pragma unroll
  for (int m = 0; m < 4; ++m)
    At[(size_t)(x0 + ty + 8 * m) * N + y0 + tx] = tile[tx][ty + 8 * m];
  if (blockIdx.x == 0 && blockIdx.y == 0 && tx == 0 && ty == 0) {
    float ld = logd[0];
    ld = fminf(fmaxf(ld, logf(1e-3f)), logf(0.1f));
    wdelta[0] = expf(ld);
  }
  if (blockIdx.y == 0 && ty == 0)
    W[blockIdx.x * 32 + tx] = C[blockIdx.x * 32 + tx];
}

__global__ __launch_bounds__(256) void k_solve(const float* __restrict__ At,
                                               const float* __restrict__ wdelta,
                                               const float* __restrict__ Bm,
                                               float* __restrict__ Ad,
                                               float* __restrict__ V) {
  int j = blockIdx.x;  // 0..511: Ad column; 512: Bd
  int tid = threadIdx.x;
  int r0 = tid, r1 = tid + 256;
  float delta = wdelta[0];
  float half = 0.5f * delta;
  __shared__ float xsh[2];
  int kstart;
  float x0, x1;
  if (j < N) {
    kstart = j;
    x0 = (r0 == j) ? 1.0f + half * At[(size_t)j * N + j]
       : (r0 > j ? half * At[(size_t)j * N + r0] : 0.0f);
    x1 = (r1 == j) ? 1.0f + half * At[(size_t)j * N + j]
       : (r1 > j ? half * At[(size_t)j * N + r1] : 0.0f);
  } else {
    kstart = 0;
    x0 = delta * Bm[r0];
    x1 = delta * Bm[r1];
  }
  float dinv0 = 1.0f / (1.0f - half * At[(size_t)r0 * N + r0]);
  float dinv1 = 1.0f / (1.0f - half * At[(size_t)r1 * N + r1]);
  if (r0 == kstart) { x0 *= dinv0; xsh[kstart & 1] = x0; }
  if (r1 == kstart) { x1 *= dinv1; xsh[kstart & 1] = x1; }
  float a0 = At[(size_t)kstart * N + r0];
  float a1 = At[(size_t)kstart * N + r1];
  __syncthreads();
  for (int kk = kstart; kk < N; ++kk) {
    float xk = xsh[kk & 1];
    float an0 = 0.0f, an1 = 0.0f;
    if (kk + 1 < N) {
      an0 = At[(size_t)(kk + 1) * N + r0];
      an1 = At[(size_t)(kk + 1) * N + r1];
    }
    if (r0 > kk) x0 += half * a0 * xk;
    if (r1 > kk) x1 += half * a1 * xk;
    if (r0 == kk + 1) { x0 *= dinv0; xsh[(kk + 1) & 1] = x0; }
    if (r1 == kk + 1) { x1 *= dinv1; xsh[(kk + 1) & 1] = x1; }
    a0 = an0; a1 = an1;
    __syncthreads();
  }
  if (j < N) {
    Ad[(size_t)r0 * N + j] = (r0 >= j) ? x0 : 0.0f;
    Ad[(size_t)r1 * N + j] = (r1 >= j) ? x1 : 0.0f;
  } else {
    V[r0] = x0;
    V[r1] = x1;
  }
}

__global__ __launch_bounds__(256) void k_matsq(const float* __restrict__ P,
                                               float* __restrict__ Q) {
  int bi = blockIdx.y, bj = blockIdx.x;
  int tid = threadIdx.x;
  int tx = tid & 31, ty = tid >> 5;
  if (bi < bj) {
#pragma unroll
    for (int m = 0; m < 4; ++m)
      Q[(size_t)(bi * 32 + ty + 8 * m) * N + bj * 32 + tx] = 0.0f;
    return;
  }
  __shared__ float As[32][33], Bs[32][33];
  float acc[4] = {0.0f, 0.0f, 0.0f, 0.0f};
  for (int kb = bj; kb <= bi; ++kb) {
#pragma unroll
    for (int m = 0; m < 4; ++m) {
      As[ty + 8 * m][tx] = P[(size_t)(bi * 32 + ty + 8 * m) * N + kb * 32 + tx];
      Bs[ty + 8 * m][tx] = P[(size_t)(kb * 32 + ty + 8 * m) * N + bj * 32 + tx];
    }
    __syncthreads();
#pragma unroll
    for (int kk = 0; kk < 32; ++kk) {
      float b = Bs[kk][tx];
#pragma unroll
      for (int m = 0; m < 4; ++m) acc[m] += As[ty + 8 * m][kk] * b;
    }
    __syncthreads();
  }
#pragma unroll
  for (int m = 0; m < 4; ++m)
    Q[(size_t)(bi * 32 + ty + 8 * m) * N + bj * 32 + tx] = acc[m];
}

__global__ __launch_bounds__(256) void k_vstep(const float* __restrict__ P,
                                               float* __restrict__ V,
                                               int base) {
  __shared__ float vc[N];
  int c = blockIdx.x;
  int tid = threadIdx.x;
  vc[tid] = V[(size_t)c * N + tid];
  vc[tid + 256] = V[(size_t)c * N + tid + 256];
  __syncthreads();
  int row = blockIdx.y * 256 + tid;
  const float* Pr = P + (size_t)row * N;
  float acc = 0.0f;
  for (int k = 0; k <= row; ++k) acc += Pr[k] * vc[k];
  V[(size_t)(base + c) * N + row] = acc;
}

__global__ __launch_bounds__(256) void k_wstep(const float* __restrict__ P,
                                               float* __restrict__ W,
                                               int base) {
  __shared__ float wq[N];
  int q = blockIdx.x;
  int tid = threadIdx.x;
  wq[tid] = W[(size_t)q * N + tid];
  wq[tid + 256] = W[(size_t)q * N + tid + 256];
  __syncthreads();
  int c = blockIdx.y * 256 + tid;
  float acc = 0.0f;
  for (int k = 0; k < N; ++k) acc += wq[k] * P[(size_t)k * N + c];
  W[(size_t)(base + q) * N + c] = acc;
}

__global__ __launch_bounds__(128) void k_kfinal(const float* __restrict__ W,
                                                const float* __restrict__ V,
                                                float* __restrict__ kvec) {
  __shared__ float wq[N];
  int q = blockIdx.x;
  int tid = threadIdx.x;
  for (int i = tid; i < N; i += 128) wq[i] = W[(size_t)q * N + i];
  __syncthreads();
  const float* Vr = V + (size_t)tid * N;
  float acc = 0.0f;
  for (int n = 0; n < N; ++n) acc += wq[n] * Vr[n];
  kvec[q * 128 + tid] = acc;
}

// X -> bf16 A-fragments in MFMA register order.
// Atab[(bt*256+ut)*64+lane] (16B) : lane holds X[bt*16+(lane&15)][ut*32+(lane>>4)*8 + e]
__global__ __launch_bounds__(256) void k_xfrag(const float* __restrict__ X,
                                               unsigned int* __restrict__ Atab) {
  int tid = blockIdx.x * 256 + threadIdx.x;   // 65536 total
  int lane = tid & 63;
  int f = tid >> 6;                           // 0..1023 = bt*256+ut
  int bt = f >> 8, ut = f & 255;
  int row = bt * 16 + (lane & 15);
  int u0 = ut * 32 + ((lane >> 4) << 3);
  const float* xp = X + (size_t)row * L + u0;
  unsigned short v[8];
#pragma unroll
  for (int e = 0; e < 8; ++e) v[e] = f2bf(xp[e]);
  uint4v o;
  o.x = pack2(v[0], v[1]); o.y = pack2(v[2], v[3]);
  o.z = pack2(v[4], v[5]); o.w = pack2(v[6], v[7]);
  ((uint4v*)Atab)[(size_t)f * 64 + lane] = o;
}

// Toeplitz kernel -> bf16 B-fragments, one 32x16 tile per 16-aligned shift d0=16*si.
// Btab[si*64+lane] : lane holds B[u=8g+e][t=(lane&15)] = k[16*si + (lane&15) - 8g - e]
__global__ __launch_bounds__(256) void k_kfrag(const float* __restrict__ kvec,
                                               unsigned int* __restrict__ Btab) {
  int tid = blockIdx.x * 256 + threadIdx.x;   // 32768 total
  int lane = tid & 63;
  int si = tid >> 6;                          // 0..511
  int base = si * 16 + (lane & 15) - ((lane >> 4) << 3);
  unsigned short v[8];
#pragma unroll
  for (int e = 0; e < 8; ++e) {
    int idx = base - e;
    float x = (idx >= 0) ? kvec[idx] : 0.0f;
    v[e] = f2bf(x);
  }
  uint4v o;
  o.x = pack2(v[0], v[1]); o.y = pack2(v[2], v[3]);
  o.z = pack2(v[4], v[5]); o.w = pack2(v[6], v[7]);
  ((uint4v*)Btab)[(size_t)si * 64 + lane] = o;
}

// Y(64 x 8192) = X(64 x K) * Toeplitz(K x 8192) + D*X via MFMA.
// Block: one 32-wide t-tile. 8 waves = 4 batch-tiles x 2-way split-K.
__global__ __launch_bounds__(512) void k_convmm(const short8* __restrict__ Atab,
                                                const short8* __restrict__ Btab,
                                                const float* __restrict__ X,
                                                const float* __restrict__ Dp,
                                                float* __restrict__ Y) {
  int tid = threadIdx.x;
  int lane = tid & 63;
  int w = tid >> 6;
  int bt = w & 3;            // batch tile (rows 16*bt..)
  int kh = w >> 2;           // split-K half
  int blk = blockIdx.x;
  int t0 = blk * 32;
  int nsteps = blk + 1;      // u-tiles of 32
  f32x4 acc0 = {0.f, 0.f, 0.f, 0.f};
  f32x4 acc1 = {0.f, 0.f, 0.f, 0.f};
  for (int ut = kh; ut < nsteps; ut += 2) {
    short8 a = Atab[(size_t)(bt * 256 + ut) * 64 + lane];
    int si0 = 2 * (blk - ut);
    short8 b0 = Btab[(size_t)si0 * 64 + lane];
    short8 b1 = Btab[(size_t)(si0 + 1) * 64 + lane];
    acc0 = __builtin_amdgcn_mfma_f32_16x16x32_bf16(a, b0, acc0, 0, 0, 0);
    acc1 = __builtin_amdgcn_mfma_f32_16x16x32_bf16(a, b1, acc1, 0, 0, 0);
  }
  __shared__ float red[4][64][8];
  if (kh == 1) {
#pragma unroll
    for (int r = 0; r < 4; ++r) {
      red[bt][lane][r] = acc0[r];
      red[bt][lane][4 + r] = acc1[r];
    }
  }
  __syncthreads();
  if (kh == 0) {
    float D0 = Dp[0];
#pragma unroll
    for (int r = 0; r < 4; ++r) {
      int b = bt * 16 + ((lane >> 4) << 2) + r;
      int t = t0 + (lane & 15);
      size_t o0 = (size_t)b * L + t;
      Y[o0] = acc0[r] + red[bt][lane][r] + D0 * X[o0];
      Y[o0 + 16] = acc1[r] + red[bt][lane][4 + r] + D0 * X[o0 + 16];
    }
  }
}

extern "C" void kernel_launch(void* const* d_in, const int* in_sizes, int n_in,
                              void* d_out, int out_size, void* d_ws, size_t ws_size,
                              hipStream_t stream) {
  const float* X  = (const float*)d_in[0];
  const float* A  = (const float*)d_in[1];
  const float* Bm = (const float*)d_in[2];
  const float* C  = (const float*)d_in[3];
  const float* D  = (const float*)d_in[4];
  const float* ld = (const float*)d_in[5];
  float* Y = (float*)d_out;

  float* ws = (float*)d_ws;
  float* wdelta = ws;
  float* At = ws + 64;
  float* Ad = At + N * N;
  float* Pa = Ad + N * N;
  float* V  = Pa + N * N;
  float* W  = V + 128 * N;
  float* kv = W + 64 * N;

  unsigned int* Atab = (unsigned int*)At;  // dead after k_solve
  unsigned int* Btab = (unsigned int*)Ad;  // dead after k_kfinal

  k_prep<<<dim3(16, 16), dim3(32, 8), 0, stream>>>(A, ld, C, At, wdelta, W);
  k_solve<<<513, 256, 0, stream>>>(At, wdelta, Bm, Ad, V);

  float* Pcur = Ad;
  float* Poth = Pa;
  for (int j = 0; j < 7; ++j) {
    k_vstep<<<dim3(1 << j, 2), 256, 0, stream>>>(Pcur, V, 1 << j);
    k_matsq<<<dim3(16, 16), 256, 0, stream>>>(Pcur, Poth);
    float* t = Pcur; Pcur = Poth; Poth = t;
  }
  for (int i = 0; i < 6; ++i) {
    k_wstep<<<dim3(1 << i, 2), 256, 0, stream>>>(Pcur, W, 1 << i);
    if (i < 5) {
      k_matsq<<<dim3(16, 16), 256, 0, stream>>>(Pcur, Poth);
      float* t = Pcur; Pcur = Poth; Poth = t;
    }
  }
  k_kfinal<<<64, 128, 0, stream>>>(W, V, kv);

  k_xfrag<<<256, 256, 0, stream>>>(X, Atab);
  k_kfrag<<<128, 256, 0, stream>>>(kv, Btab);
  k_convmm<<<256, 512, 0, stream>>>((const short8*)Atab, (const short8*)Btab, X, D, Y);
}

// Round 3
// 567.527 us; speedup vs baseline: 1.9355x; 1.1923x over previous
//
#include <hip/hip_runtime.h>

#define N 512
#define L 8192
#define BATCH 64

#define LOG_MIN -6.907755278982137f
#define LOG_MAX -2.302585092994046f

typedef __attribute__((ext_vector_type(8))) short short8;
typedef __attribute__((ext_vector_type(4))) float f32x4;
typedef __attribute__((ext_vector_type(4))) unsigned int uint4v;

__device__ __forceinline__ float get_delta(const float* logd) {
  float ld = logd[0];
  ld = fminf(fmaxf(ld, LOG_MIN), LOG_MAX);
  return expf(ld);
}
__device__ __forceinline__ unsigned short f2bf(float x) {
  union { float f; unsigned int u; } c; c.f = x;
  unsigned int u = c.u;
  u += 0x7FFFu + ((u >> 16) & 1u);
  return (unsigned short)(u >> 16);
}
__device__ __forceinline__ unsigned int pack2(unsigned short a, unsigned short b) {
  return (unsigned int)a | ((unsigned int)b << 16);
}

// ---------------------------------------------------------------------------
// ws layout (floats):
//   0       kvec (8192)
//   8192    V    (128*512)          row 0 = Bd
//   73728   W    (64*512)           row 0 = C
//   106496  B0   (512*512)  U scratch early; Ad / squaring ping later
//   368640  B1   (512*512)  squaring pong          -> Btab aliases (131072 f)
//   630784  Xi   (512*512)  A1^-1                  -> Atab aliases (262144 f)
//   total 892928 floats = 3.57 MB (same footprint as round 2)
// ---------------------------------------------------------------------------

// Blocks 0-7: invert 64x64 diagonal blocks of A1 = I - h*A -> Xi diag.
// Blocks 8-35: zero the 28 strictly-upper 64-tiles of Xi.  Block 36: W[0]=C.
__global__ __launch_bounds__(64) void k_diaginv(const float* __restrict__ A,
                                                const float* __restrict__ C,
                                                const float* __restrict__ logd,
                                                float* __restrict__ Xi,
                                                float* __restrict__ W) {
  int b = blockIdx.x;
  int t = threadIdx.x;
  if (b >= 8) {
    if (b < 36) {
      int idx = b - 8, bi = 0, bj = 0, cnt = 0;
      for (int i = 0; i < 8; ++i)
        for (int j = i + 1; j < 8; ++j) {
          if (cnt == idx) { bi = i; bj = j; }
          ++cnt;
        }
      for (int r = 0; r < 64; ++r)
        Xi[(size_t)(bi * 64 + r) * N + bj * 64 + t] = 0.0f;
    } else {
      for (int i = t; i < N; i += 64) W[i] = C[i];
    }
    return;
  }
  float h = 0.5f * get_delta(logd);
  __shared__ float Ash[64][65];
  __shared__ float xs[64][65];
  int i0 = b * 64;
  for (int r = 0; r < 64; ++r)
    Ash[r][t] = A[(size_t)(i0 + r) * N + i0 + t];
  __syncthreads();
  // column t of inv(L), L = I - h*Ash (lower tri): forward substitution
  for (int r = 0; r < t; ++r) xs[r][t] = 0.0f;
  for (int r = t; r < 64; ++r) {
    float s;
    if (r == t) s = 1.0f;
    else {
      s = 0.0f;
      for (int k = t; k < r; ++k) s += Ash[r][k] * xs[k][t];
      s *= h;
    }
    xs[r][t] = s / (1.0f - h * Ash[r][r]);
  }
  for (int r = 0; r < 64; ++r)
    Xi[(size_t)(i0 + r) * N + i0 + t] = xs[r][t];
}

// C_ = alpha * A_ * B_  (S x S x S, S = 32*gridDim.x), batched over blockIdx.z.
// amode 0: alpha = -h (A_ is a raw-A off-diag block); amode 1: alpha = -1.
__global__ __launch_bounds__(256) void k_offmul(const float* __restrict__ Abase, int lda, int sA,
                                                const float* __restrict__ Bbase, int ldb, int sB,
                                                float* __restrict__ Cbase, int ldc, int sC,
                                                const float* __restrict__ logd, int amode) {
  int g = blockIdx.z;
  const float* A_ = Abase + (size_t)g * sA;
  const float* B_ = Bbase + (size_t)g * sB;
  float* C_ = Cbase + (size_t)g * sC;
  int S = gridDim.x * 32;
  int bi = blockIdx.y, bj = blockIdx.x;
  int tid = threadIdx.x;
  int tx = tid & 31, ty = tid >> 5;
  float alpha = (amode == 0) ? -0.5f * get_delta(logd) : -1.0f;
  __shared__ float As[32][33], Bs[32][33];
  float acc[4] = {0.f, 0.f, 0.f, 0.f};
  for (int kb = 0; kb < S; kb += 32) {
#pragma unroll
    for (int m = 0; m < 4; ++m) {
      As[ty + 8 * m][tx] = A_[(size_t)(bi * 32 + ty + 8 * m) * lda + kb + tx];
      Bs[ty + 8 * m][tx] = B_[(size_t)(kb + ty + 8 * m) * ldb + bj * 32 + tx];
    }
    __syncthreads();
#pragma unroll
    for (int kk = 0; kk < 32; ++kk) {
      float bv = Bs[kk][tx];
#pragma unroll
      for (int m = 0; m < 4; ++m) acc[m] += As[ty + 8 * m][kk] * bv;
    }
    __syncthreads();
  }
#pragma unroll
  for (int m = 0; m < 4; ++m)
    C_[(size_t)(bi * 32 + ty + 8 * m) * ldc + bj * 32 + tx] = alpha * acc[m];
}

// Ad = Xi + h*(Xi*A)  (lower tri, zeros above); block bx==16,by==0: Bd -> V[0].
__global__ __launch_bounds__(256) void k_admul(const float* __restrict__ Xi,
                                               const float* __restrict__ A,
                                               const float* __restrict__ Bm,
                                               const float* __restrict__ logd,
                                               float* __restrict__ Ad,
                                               float* __restrict__ V) {
  float delta = get_delta(logd);
  float h = 0.5f * delta;
  int tid = threadIdx.x;
  if (blockIdx.x == 16) {
    if (blockIdx.y != 0) return;
    __shared__ float bs[N];
    bs[tid] = Bm[tid]; bs[tid + 256] = Bm[tid + 256];
    __syncthreads();
    for (int rr = 0; rr < 2; ++rr) {
      int row = rr * 256 + tid;
      const float* Xr = Xi + (size_t)row * N;
      float acc = 0.f;
      for (int k = 0; k <= row; ++k) acc += Xr[k] * bs[k];
      V[row] = delta * acc;
    }
    return;
  }
  int bi = blockIdx.y, bj = blockIdx.x;
  int tx = tid & 31, ty = tid >> 5;
  if (bi < bj) {
#pragma unroll
    for (int m = 0; m < 4; ++m)
      Ad[(size_t)(bi * 32 + ty + 8 * m) * N + bj * 32 + tx] = 0.f;
    return;
  }
  __shared__ float As[32][33], Bs[32][33];
  float acc[4] = {0.f, 0.f, 0.f, 0.f};
  for (int kb = bj; kb <= bi; ++kb) {
#pragma unroll
    for (int m = 0; m < 4; ++m) {
      As[ty + 8 * m][tx] = Xi[(size_t)(bi * 32 + ty + 8 * m) * N + kb * 32 + tx];
      Bs[ty + 8 * m][tx] = A[(size_t)(kb * 32 + ty + 8 * m) * N + bj * 32 + tx];
    }
    __syncthreads();
#pragma unroll
    for (int kk = 0; kk < 32; ++kk) {
      float bv = Bs[kk][tx];
#pragma unroll
      for (int m = 0; m < 4; ++m) acc[m] += As[ty + 8 * m][kk] * bv;
    }
    __syncthreads();
  }
#pragma unroll
  for (int m = 0; m < 4; ++m) {
    size_t o = (size_t)(bi * 32 + ty + 8 * m) * N + bj * 32 + tx;
    Ad[o] = h * acc[m] + Xi[o];
  }
}

// Shared squaring body: Q = P*P for lower-tri 512 (32x32 tiles, zeros above).
__device__ __forceinline__ void sq_body(const float* __restrict__ P,
                                        float* __restrict__ Q,
                                        int bi, int bj, int tid) {
  int tx = tid & 31, ty = tid >> 5;
  if (bi < bj) {
#pragma unroll
    for (int m = 0; m < 4; ++m)
      Q[(size_t)(bi * 32 + ty + 8 * m) * N + bj * 32 + tx] = 0.f;
    return;
  }
  __shared__ float As[32][33], Bs[32][33];
  float acc[4] = {0.f, 0.f, 0.f, 0.f};
  for (int kb = bj; kb <= bi; ++kb) {
#pragma unroll
    for (int m = 0; m < 4; ++m) {
      As[ty + 8 * m][tx] = P[(size_t)(bi * 32 + ty + 8 * m) * N + kb * 32 + tx];
      Bs[ty + 8 * m][tx] = P[(size_t)(kb * 32 + ty + 8 * m) * N + bj * 32 + tx];
    }
    __syncthreads();
#pragma unroll
    for (int kk = 0; kk < 32; ++kk) {
      float bv = Bs[kk][tx];
#pragma unroll
      for (int m = 0; m < 4; ++m) acc[m] += As[ty + 8 * m][kk] * bv;
    }
    __syncthreads();
  }
#pragma unroll
  for (int m = 0; m < 4; ++m)
    Q[(size_t)(bi * 32 + ty + 8 * m) * N + bj * 32 + tx] = acc[m];
}

// Blocks 0-255: Q = P*P. Blocks 256+: vstep c: V[base+c] = P*V[c].
__global__ __launch_bounds__(256) void k_sqv(const float* __restrict__ P,
                                             float* __restrict__ Q,
                                             float* __restrict__ V, int base) {
  int bx = blockIdx.x;
  int tid = threadIdx.x;
  if (bx < 256) { sq_body(P, Q, bx >> 4, bx & 15, tid); return; }
  int c = bx - 256;
  __shared__ float vc[N], vout[N];
  if (tid < 128)
    ((float4*)vc)[tid] = ((const float4*)(V + (size_t)c * N))[tid];
  __syncthreads();
  int w = tid >> 6, lane = tid & 63, sub = lane & 15, quad = lane >> 4;
  for (int pass = 0; pass < 32; ++pass) {
    int row = w * 128 + pass * 4 + quad;
    const float4* Pr = (const float4*)(P + (size_t)row * N);
    float acc = 0.f;
#pragma unroll
    for (int u = 0; u < 8; ++u) {
      float4 a = Pr[sub * 8 + u];
      float4 bvv = ((const float4*)vc)[sub * 8 + u];
      acc += a.x * bvv.x + a.y * bvv.y + a.z * bvv.z + a.w * bvv.w;
    }
    acc += __shfl_xor(acc, 1, 64);
    acc += __shfl_xor(acc, 2, 64);
    acc += __shfl_xor(acc, 4, 64);
    acc += __shfl_xor(acc, 8, 64);
    if (sub == 0) vout[row] = acc;
  }
  __syncthreads();
  V[(size_t)(base + c) * N + tid] = vout[tid];
  V[(size_t)(base + c) * N + tid + 256] = vout[tid + 256];
}

// Blocks 0..nsq-1: Q = P*P. Blocks nsq+: wstep: W[base+q] = W[q]*P.
__global__ __launch_bounds__(256) void k_sqw(const float* __restrict__ P,
                                             float* __restrict__ Q,
                                             float* __restrict__ W,
                                             int base, int nsq) {
  int bx = blockIdx.x;
  int tid = threadIdx.x;
  if (bx < nsq) { sq_body(P, Q, bx >> 4, bx & 15, tid); return; }
  int idx = bx - nsq;
  int q = idx >> 1, half = idx & 1;
  __shared__ float wq[N];
  if (tid < 128)
    ((float4*)wq)[tid] = ((const float4*)(W + (size_t)q * N))[tid];
  __syncthreads();
  int c = half * 256 + tid;
  const float* Pc = P + c;
  float acc = 0.f;
#pragma unroll 8
  for (int k = 0; k < N; ++k) acc += wq[k] * Pc[(size_t)k * N];
  W[(size_t)(base + q) * N + c] = acc;
}

__global__ __launch_bounds__(128) void k_kfinal(const float* __restrict__ W,
                                                const float* __restrict__ V,
                                                float* __restrict__ kvec) {
  __shared__ float wq[N];
  int q = blockIdx.x;
  int tid = threadIdx.x;
  for (int i = tid; i < N; i += 128) wq[i] = W[(size_t)q * N + i];
  __syncthreads();
  const float* Vr = V + (size_t)tid * N;
  float acc = 0.f;
  for (int n = 0; n < N; ++n) acc += wq[n] * Vr[n];
  kvec[q * 128 + tid] = acc;
}

// X -> bf16 A-fragments in MFMA register order.
__global__ __launch_bounds__(256) void k_xfrag(const float* __restrict__ X,
                                               unsigned int* __restrict__ Atab) {
  int tid = blockIdx.x * 256 + threadIdx.x;
  int lane = tid & 63;
  int f = tid >> 6;
  int bt = f >> 8, ut = f & 255;
  int row = bt * 16 + (lane & 15);
  int u0 = ut * 32 + ((lane >> 4) << 3);
  const float* xp = X + (size_t)row * L + u0;
  unsigned short v[8];
#pragma unroll
  for (int e = 0; e < 8; ++e) v[e] = f2bf(xp[e]);
  uint4v o;
  o.x = pack2(v[0], v[1]); o.y = pack2(v[2], v[3]);
  o.z = pack2(v[4], v[5]); o.w = pack2(v[6], v[7]);
  ((uint4v*)Atab)[(size_t)f * 64 + lane] = o;
}

// Toeplitz kernel -> bf16 B-fragments per 16-aligned shift.
__global__ __launch_bounds__(256) void k_kfrag(const float* __restrict__ kvec,
                                               unsigned int* __restrict__ Btab) {
  int tid = blockIdx.x * 256 + threadIdx.x;
  int lane = tid & 63;
  int si = tid >> 6;
  int base = si * 16 + (lane & 15) - ((lane >> 4) << 3);
  unsigned short v[8];
#pragma unroll
  for (int e = 0; e < 8; ++e) {
    int idx = base - e;
    float x = (idx >= 0) ? kvec[idx] : 0.0f;
    v[e] = f2bf(x);
  }
  uint4v o;
  o.x = pack2(v[0], v[1]); o.y = pack2(v[2], v[3]);
  o.z = pack2(v[4], v[5]); o.w = pack2(v[6], v[7]);
  ((uint4v*)Btab)[(size_t)si * 64 + lane] = o;
}

// Y(64 x 8192) = X * Toeplitz + D*X via MFMA (split-K over 2 wave-groups).
__global__ __launch_bounds__(512) void k_convmm(const short8* __restrict__ Atab,
                                                const short8* __restrict__ Btab,
                                                const float* __restrict__ X,
                                                const float* __restrict__ Dp,
                                                float* __restrict__ Y) {
  int tid = threadIdx.x;
  int lane = tid & 63;
  int w = tid >> 6;
  int bt = w & 3;
  int kh = w >> 2;
  int blk = blockIdx.x;
  int t0 = blk * 32;
  int nsteps = blk + 1;
  f32x4 acc0 = {0.f, 0.f, 0.f, 0.f};
  f32x4 acc1 = {0.f, 0.f, 0.f, 0.f};
  for (int ut = kh; ut < nsteps; ut += 2) {
    short8 a = Atab[(size_t)(bt * 256 + ut) * 64 + lane];
    int si0 = 2 * (blk - ut);
    short8 b0 = Btab[(size_t)si0 * 64 + lane];
    short8 b1 = Btab[(size_t)(si0 + 1) * 64 + lane];
    acc0 = __builtin_amdgcn_mfma_f32_16x16x32_bf16(a, b0, acc0, 0, 0, 0);
    acc1 = __builtin_amdgcn_mfma_f32_16x16x32_bf16(a, b1, acc1, 0, 0, 0);
  }
  __shared__ float red[4][64][8];
  if (kh == 1) {
#pragma unroll
    for (int r = 0; r < 4; ++r) {
      red[bt][lane][r] = acc0[r];
      red[bt][lane][4 + r] = acc1[r];
    }
  }
  __syncthreads();
  if (kh == 0) {
    float D0 = Dp[0];
#pragma unroll
    for (int r = 0; r < 4; ++r) {
      int b = bt * 16 + ((lane >> 4) << 2) + r;
      int t = t0 + (lane & 15);
      size_t o0 = (size_t)b * L + t;
      Y[o0] = acc0[r] + red[bt][lane][r] + D0 * X[o0];
      Y[o0 + 16] = acc1[r] + red[bt][lane][4 + r] + D0 * X[o0 + 16];
    }
  }
}

extern "C" void kernel_launch(void* const* d_in, const int* in_sizes, int n_in,
                              void* d_out, int out_size, void* d_ws, size_t ws_size,
                              hipStream_t stream) {
  const float* X  = (const float*)d_in[0];
  const float* A  = (const float*)d_in[1];
  const float* Bm = (const float*)d_in[2];
  const float* C  = (const float*)d_in[3];
  const float* D  = (const float*)d_in[4];
  const float* ld = (const float*)d_in[5];
  float* Y = (float*)d_out;

  float* ws = (float*)d_ws;
  float* kv = ws;                  // 8192
  float* V  = ws + 8192;           // 128*512
  float* W  = ws + 73728;          // 64*512
  float* B0 = ws + 106496;         // 512*512 (U scratch -> Ad / ping)
  float* B1 = ws + 368640;         // 512*512 (pong)
  float* Xi = ws + 630784;         // 512*512 (A1inv)
  float* U  = B0;

  unsigned int* Atab = (unsigned int*)Xi;  // Xi dead after k_admul
  unsigned int* Btab = (unsigned int*)B1;  // B1 dead after last squaring

  // --- A1 inverse via blocked triangular inversion ---
  k_diaginv<<<37, 64, 0, stream>>>(A, C, ld, Xi, W);
  // level 1 (S=64, 4 batches)
  k_offmul<<<dim3(2, 2, 4), 256, 0, stream>>>(A + 64 * N, N, 128 * (N + 1),
                                              Xi, N, 128 * (N + 1),
                                              U, 64, 64 * 64, ld, 0);
  k_offmul<<<dim3(2, 2, 4), 256, 0, stream>>>(Xi + 64 * (N + 1), N, 128 * (N + 1),
                                              U, 64, 64 * 64,
                                              Xi + 64 * N, N, 128 * (N + 1), ld, 1);
  // level 2 (S=128, 2 batches)
  k_offmul<<<dim3(4, 4, 2), 256, 0, stream>>>(A + 128 * N, N, 256 * (N + 1),
                                              Xi, N, 256 * (N + 1),
                                              U, 128, 128 * 128, ld, 0);
  k_offmul<<<dim3(4, 4, 2), 256, 0, stream>>>(Xi + 128 * (N + 1), N, 256 * (N + 1),
                                              U, 128, 128 * 128,
                                              Xi + 128 * N, N, 256 * (N + 1), ld, 1);
  // level 3 (S=256, 1 batch)
  k_offmul<<<dim3(8, 8, 1), 256, 0, stream>>>(A + 256 * N, N, 0,
                                              Xi, N, 0,
                                              U, 256, 0, ld, 0);
  k_offmul<<<dim3(8, 8, 1), 256, 0, stream>>>(Xi + 256 * (N + 1), N, 0,
                                              U, 256, 0,
                                              Xi + 256 * N, N, 0, ld, 1);
  // Ad = Xi + h*Xi*A -> B0 ; Bd -> V[0]
  k_admul<<<dim3(17, 16), 256, 0, stream>>>(Xi, A, Bm, ld, B0, V);

  // --- fused squaring + Krylov doubling chain ---
  k_sqv<<<256 + 1, 256, 0, stream>>>(B0, B1, V, 1);    // B1 = Ad^2
  k_sqv<<<256 + 2, 256, 0, stream>>>(B1, B0, V, 2);    // B0 = Ad^4
  k_sqv<<<256 + 4, 256, 0, stream>>>(B0, B1, V, 4);    // B1 = Ad^8
  k_sqv<<<256 + 8, 256, 0, stream>>>(B1, B0, V, 8);    // B0 = Ad^16
  k_sqv<<<256 + 16, 256, 0, stream>>>(B0, B1, V, 16);  // B1 = Ad^32
  k_sqv<<<256 + 32, 256, 0, stream>>>(B1, B0, V, 32);  // B0 = Ad^64
  k_sqv<<<256 + 64, 256, 0, stream>>>(B0, B1, V, 64);  // B1 = Ad^128
  k_sqw<<<256 + 2, 256, 0, stream>>>(B1, B0, W, 1, 256);   // B0 = Ad^256
  k_sqw<<<256 + 4, 256, 0, stream>>>(B0, B1, W, 2, 256);   // B1 = Ad^512
  k_sqw<<<256 + 8, 256, 0, stream>>>(B1, B0, W, 4, 256);   // B0 = Ad^1024
  k_sqw<<<256 + 16, 256, 0, stream>>>(B0, B1, W, 8, 256);  // B1 = Ad^2048
  k_sqw<<<256 + 32, 256, 0, stream>>>(B1, B0, W, 16, 256); // B0 = Ad^4096
  k_sqw<<<64, 256, 0, stream>>>(B0, (float*)nullptr, W, 32, 0);
  k_kfinal<<<64, 128, 0, stream>>>(W, V, kv);

  // --- Toeplitz conv via MFMA ---
  k_xfrag<<<256, 256, 0, stream>>>(X, Atab);
  k_kfrag<<<128, 256, 0, stream>>>(kv, Btab);
  k_convmm<<<256, 512, 0, stream>>>((const short8*)Atab, (const short8*)Btab, X, D, Y);
}

// Round 4
// 530.747 us; speedup vs baseline: 2.0697x; 1.0693x over previous
//
#include <hip/hip_runtime.h>

#define N 512
#define L 8192

#define LOG_MIN -6.907755278982137f
#define LOG_MAX -2.302585092994046f

typedef __attribute__((ext_vector_type(8))) short short8;
typedef __attribute__((ext_vector_type(4))) float f32x4;
typedef __attribute__((ext_vector_type(4))) unsigned int uint4v;

__device__ __forceinline__ float get_delta(const float* logd) {
  float ld = logd[0];
  ld = fminf(fmaxf(ld, LOG_MIN), LOG_MAX);
  return expf(ld);
}
__device__ __forceinline__ unsigned short f2bf(float x) {
  union { float f; unsigned int u; } c; c.f = x;
  unsigned int u = c.u;
  u += 0x7FFFu + ((u >> 16) & 1u);
  return (unsigned short)(u >> 16);
}
__device__ __forceinline__ unsigned int pack2(unsigned short a, unsigned short b) {
  return (unsigned int)a | ((unsigned int)b << 16);
}

// ---------------------------------------------------------------------------
// ws layout (floats):
//   0       kvec (8192)
//   8192    V    (128*512)   row 0 = Bd
//   73728   W    (64*512)    row 0 = C
//   106496  B0   (512*512)   U scratch early; squaring ping
//   368640  B1   (512*512)   squaring pong    -> Btab aliases
//   630784  Xi   (512*512)   A1^-1            -> Atab aliases
// ---------------------------------------------------------------------------

// Blocks 0-15: invert 32x32 diag blocks of A1 = I - h*A (wave-parallel substitution).
// 16-43: zero strict-upper 64-tiles. 44-51: zero upper-right 32x32 of diag 64-tiles.
// 52: W[0] = C.
__global__ __launch_bounds__(256) void k_diaginv(const float* __restrict__ A,
                                                 const float* __restrict__ C,
                                                 const float* __restrict__ logd,
                                                 float* __restrict__ Xi,
                                                 float* __restrict__ W) {
  int b = blockIdx.x, tid = threadIdx.x;
  if (b < 16) {
    __shared__ float Ash[32][33];
    __shared__ float xs[32][33];
    __shared__ float dinv[32];
    float h = 0.5f * get_delta(logd);
    int i0 = b * 32;
    {
      int r = tid >> 3, c4 = (tid & 7) * 4;
      float4 v = *(const float4*)(A + (size_t)(i0 + r) * N + i0 + c4);
      Ash[r][c4] = v.x; Ash[r][c4 + 1] = v.y; Ash[r][c4 + 2] = v.z; Ash[r][c4 + 3] = v.w;
    }
    for (int i = tid; i < 32 * 33; i += 256) ((float*)xs)[i] = 0.f;
    __syncthreads();
    if (tid < 32) dinv[tid] = 1.f / (1.f - h * Ash[tid][tid]);
    __syncthreads();
    int t = tid >> 3, kl = tid & 7;
    for (int r = 0; r < 32; ++r) {
      float s = 0.f;
      for (int k = t + kl; k < r; k += 8) s += Ash[r][k] * xs[k][t];
      s += __shfl_xor(s, 1, 64);
      s += __shfl_xor(s, 2, 64);
      s += __shfl_xor(s, 4, 64);
      if (kl == 0 && t <= r)
        xs[r][t] = (((r == t) ? 1.f : 0.f) + h * s) * dinv[r];
      __syncthreads();
    }
    {
      int r = tid >> 3, c4 = (tid & 7) * 4;
      float4 v = {xs[r][c4], xs[r][c4 + 1], xs[r][c4 + 2], xs[r][c4 + 3]};
      *(float4*)(Xi + (size_t)(i0 + r) * N + i0 + c4) = v;
    }
    return;
  }
  if (b < 44) {
    int idx = b - 16, bi = 0, bj = 0, cnt = 0;
    for (int i = 0; i < 8; ++i)
      for (int j = i + 1; j < 8; ++j) { if (cnt == idx) { bi = i; bj = j; } ++cnt; }
    int r = tid >> 2, cq = (tid & 3) * 16;
    float4 z = {0.f, 0.f, 0.f, 0.f};
#pragma unroll
    for (int j = 0; j < 4; ++j)
      *(float4*)(Xi + (size_t)(bi * 64 + r) * N + bj * 64 + cq + 4 * j) = z;
    return;
  }
  if (b < 52) {
    int d = b - 44;
    int r = tid >> 3, c4 = (tid & 7) * 4;
    float4 z = {0.f, 0.f, 0.f, 0.f};
    *(float4*)(Xi + (size_t)(d * 64 + r) * N + d * 64 + 32 + c4) = z;
    return;
  }
  for (int i = tid; i < N; i += 256) W[i] = C[i];
}

// C_ = alpha * A_ * B_  (S x S x S, S = 32*gridDim.x), batched over blockIdx.z.
__global__ __launch_bounds__(256) void k_offmul(const float* __restrict__ Abase, int lda, int sA,
                                                const float* __restrict__ Bbase, int ldb, int sB,
                                                float* __restrict__ Cbase, int ldc, int sC,
                                                const float* __restrict__ logd, int amode) {
  int g = blockIdx.z;
  const float* A_ = Abase + (size_t)g * sA;
  const float* B_ = Bbase + (size_t)g * sB;
  float* C_ = Cbase + (size_t)g * sC;
  int S = gridDim.x * 32;
  int bi = blockIdx.y, bj = blockIdx.x;
  int tid = threadIdx.x;
  int tx = tid & 31, ty = tid >> 5;
  float alpha = (amode == 0) ? -0.5f * get_delta(logd) : -1.0f;
  __shared__ float As[32][33], Bs[32][33];
  float acc[4] = {0.f, 0.f, 0.f, 0.f};
  for (int kb = 0; kb < S; kb += 32) {
#pragma unroll
    for (int m = 0; m < 4; ++m) {
      As[ty + 8 * m][tx] = A_[(size_t)(bi * 32 + ty + 8 * m) * lda + kb + tx];
      Bs[ty + 8 * m][tx] = B_[(size_t)(kb + ty + 8 * m) * ldb + bj * 32 + tx];
    }
    __syncthreads();
#pragma unroll
    for (int kk = 0; kk < 32; ++kk) {
      float bv = Bs[kk][tx];
#pragma unroll
      for (int m = 0; m < 4; ++m) acc[m] += As[ty + 8 * m][kk] * bv;
    }
    __syncthreads();
  }
#pragma unroll
  for (int m = 0; m < 4; ++m)
    C_[(size_t)(bi * 32 + ty + 8 * m) * ldc + bj * 32 + tx] = alpha * acc[m];
}

// 64x64-tile lower-tri squaring: Q = P*P (first: P := 2*Pin - I read-transform).
__device__ void sq64(const float* __restrict__ P, float* __restrict__ Q,
                     int bi, int bj, int tid, int first, float* sm) {
  if (bi < bj) {
    int r = tid >> 2, cq = (tid & 3) * 16;
    float4 z = {0.f, 0.f, 0.f, 0.f};
#pragma unroll
    for (int j = 0; j < 4; ++j)
      *(float4*)(Q + (size_t)(bi * 64 + r) * N + bj * 64 + cq + 4 * j) = z;
    return;
  }
  float* Ast = sm;            // [32][68] : Ast[k][r] = P[bi*64+r][kb+k]
  float* Bs = sm + 32 * 68;   // [32][64]
  int tx = tid & 15, ty = tid >> 4;
  float acc[4][4];
#pragma unroll
  for (int i = 0; i < 4; ++i)
#pragma unroll
    for (int j = 0; j < 4; ++j) acc[i][j] = 0.f;
  int ar = tid >> 2, aq = tid & 3;
  int bk = tid >> 3, bc = (tid & 7) * 8;
  for (int kb = bj * 64; kb < (bi + 1) * 64; kb += 32) {
    const float* asrc = P + (size_t)(bi * 64 + ar) * N + kb + aq * 8;
    float av[8];
    *(float4*)&av[0] = *(const float4*)asrc;
    *(float4*)&av[4] = *(const float4*)(asrc + 4);
    const float* bsrc = P + (size_t)(kb + bk) * N + bj * 64 + bc;
    float bv[8];
    *(float4*)&bv[0] = *(const float4*)bsrc;
    *(float4*)&bv[4] = *(const float4*)(bsrc + 4);
    if (first) {
      int gra = bi * 64 + ar, gca = kb + aq * 8;
      int grb = kb + bk, gcb = bj * 64 + bc;
#pragma unroll
      for (int j = 0; j < 8; ++j) {
        av[j] = 2.f * av[j] - ((gra == gca + j) ? 1.f : 0.f);
        bv[j] = 2.f * bv[j] - ((grb == gcb + j) ? 1.f : 0.f);
      }
    }
#pragma unroll
    for (int j = 0; j < 8; ++j) Ast[(aq * 8 + j) * 68 + ar] = av[j];
    *(float4*)&Bs[bk * 64 + bc] = *(float4*)&bv[0];
    *(float4*)&Bs[bk * 64 + bc + 4] = *(float4*)&bv[4];
    __syncthreads();
#pragma unroll 8
    for (int k = 0; k < 32; ++k) {
      float4 a = *(const float4*)&Ast[k * 68 + 4 * ty];
      float4 bb = *(const float4*)&Bs[k * 64 + 4 * tx];
      float ai[4] = {a.x, a.y, a.z, a.w};
      float bj4[4] = {bb.x, bb.y, bb.z, bb.w};
#pragma unroll
      for (int i = 0; i < 4; ++i)
#pragma unroll
        for (int j = 0; j < 4; ++j) acc[i][j] = fmaf(ai[i], bj4[j], acc[i][j]);
    }
    __syncthreads();
  }
#pragma unroll
  for (int i = 0; i < 4; ++i) {
    float4 v = {acc[i][0], acc[i][1], acc[i][2], acc[i][3]};
    *(float4*)(Q + (size_t)(bi * 64 + 4 * ty + i) * N + bj * 64 + 4 * tx) = v;
  }
}

__device__ void vstep_body(const float* __restrict__ P, float* __restrict__ V,
                           int base, int c, int tid, float* sm) {
  float* vc = sm;
  float* vout = sm + N;
  if (tid < 128) ((float4*)vc)[tid] = ((const float4*)(V + (size_t)c * N))[tid];
  __syncthreads();
  int w = tid >> 6, lane = tid & 63, sub = lane & 15, quad = lane >> 4;
  for (int pass = 0; pass < 32; ++pass) {
    int row = w * 128 + pass * 4 + quad;
    const float4* Pr = (const float4*)(P + (size_t)row * N);
    float acc = 0.f;
#pragma unroll
    for (int u = 0; u < 8; ++u) {
      float4 a = Pr[sub * 8 + u];
      float4 bv = ((const float4*)vc)[sub * 8 + u];
      acc += a.x * bv.x + a.y * bv.y + a.z * bv.z + a.w * bv.w;
    }
    acc += __shfl_xor(acc, 1, 64);
    acc += __shfl_xor(acc, 2, 64);
    acc += __shfl_xor(acc, 4, 64);
    acc += __shfl_xor(acc, 8, 64);
    if (sub == 0) vout[row] = acc;
  }
  __syncthreads();
  V[(size_t)(base + c) * N + tid] = vout[tid];
  V[(size_t)(base + c) * N + tid + 256] = vout[tid + 256];
}

// Special block of first k_sqv: V[0] = delta*Xi*Bm; V[1] = (2Xi-I)V[0].
__device__ void vspecial(const float* __restrict__ Xi, float* __restrict__ V,
                         const float* __restrict__ Bm, const float* __restrict__ logd,
                         int tid, float* sm) {
  float* bs = sm;
  float* v0 = sm + N;
  float* v1 = sm + 2 * N;
  float delta = get_delta(logd);
  if (tid < 128) ((float4*)bs)[tid] = ((const float4*)Bm)[tid];
  __syncthreads();
  int w = tid >> 6, lane = tid & 63, sub = lane & 15, quad = lane >> 4;
  for (int pass = 0; pass < 32; ++pass) {
    int row = w * 128 + pass * 4 + quad;
    const float4* Pr = (const float4*)(Xi + (size_t)row * N);
    float acc = 0.f;
#pragma unroll
    for (int u = 0; u < 8; ++u) {
      float4 a = Pr[sub * 8 + u];
      float4 bv = ((const float4*)bs)[sub * 8 + u];
      acc += a.x * bv.x + a.y * bv.y + a.z * bv.z + a.w * bv.w;
    }
    acc += __shfl_xor(acc, 1, 64);
    acc += __shfl_xor(acc, 2, 64);
    acc += __shfl_xor(acc, 4, 64);
    acc += __shfl_xor(acc, 8, 64);
    if (sub == 0) v0[row] = delta * acc;
  }
  __syncthreads();
  for (int pass = 0; pass < 32; ++pass) {
    int row = w * 128 + pass * 4 + quad;
    const float4* Pr = (const float4*)(Xi + (size_t)row * N);
    float acc = 0.f;
#pragma unroll
    for (int u = 0; u < 8; ++u) {
      float4 a = Pr[sub * 8 + u];
      float4 bv = ((const float4*)v0)[sub * 8 + u];
      acc += a.x * bv.x + a.y * bv.y + a.z * bv.z + a.w * bv.w;
    }
    acc += __shfl_xor(acc, 1, 64);
    acc += __shfl_xor(acc, 2, 64);
    acc += __shfl_xor(acc, 4, 64);
    acc += __shfl_xor(acc, 8, 64);
    if (sub == 0) v1[row] = 2.f * acc - v0[row];
  }
  __syncthreads();
  V[tid] = v0[tid];
  V[tid + 256] = v0[tid + 256];
  V[N + tid] = v1[tid];
  V[N + tid + 256] = v1[tid + 256];
}

// Blocks 0-63: 64-tile squaring. Blocks 64+: vstep (or Bd special when first).
__global__ __launch_bounds__(256) void k_sqv(const float* __restrict__ P,
                                             float* __restrict__ Q,
                                             float* __restrict__ V, int base, int first,
                                             const float* __restrict__ Bm,
                                             const float* __restrict__ logd) {
  __shared__ float sm[32 * 68 + 32 * 64];
  int bx = blockIdx.x, tid = threadIdx.x;
  if (bx < 64) { sq64(P, Q, bx >> 3, bx & 7, tid, first, sm); return; }
  if (first) { vspecial(P, V, Bm, logd, tid, sm); return; }
  vstep_body(P, V, base, bx - 64, tid, sm);
}

// Blocks 0..nsq-1: squaring. Blocks nsq+: wstep halves: W[base+q] = W[q]*P.
__global__ __launch_bounds__(256) void k_sqw(const float* __restrict__ P,
                                             float* __restrict__ Q,
                                             float* __restrict__ W, int base, int nsq) {
  __shared__ float sm[32 * 68 + 32 * 64];
  int bx = blockIdx.x, tid = threadIdx.x;
  if (bx < nsq) { sq64(P, Q, bx >> 3, bx & 7, tid, 0, sm); return; }
  int idx = bx - nsq, q = idx >> 1, half = idx & 1;
  float* wq = sm;
  if (tid < 128) ((float4*)wq)[tid] = ((const float4*)(W + (size_t)q * N))[tid];
  __syncthreads();
  int c = half * 256 + tid;
  const float* Pc = P + c;
  float acc = 0.f;
#pragma unroll 8
  for (int k = 0; k < N; ++k) acc += wq[k] * Pc[(size_t)k * N];
  W[(size_t)(base + q) * N + c] = acc;
}

__global__ __launch_bounds__(128) void k_kfinal(const float* __restrict__ W,
                                                const float* __restrict__ V,
                                                float* __restrict__ kvec) {
  __shared__ float wq[N];
  int q = blockIdx.x;
  int tid = threadIdx.x;
  for (int i = tid; i < N; i += 128) wq[i] = W[(size_t)q * N + i];
  __syncthreads();
  const float* Vr = V + (size_t)tid * N;
  float acc = 0.f;
  for (int n = 0; n < N; ++n) acc += wq[n] * Vr[n];
  kvec[q * 128 + tid] = acc;
}

// Fused: blocks 0-255 -> X A-frags; blocks 256-383 -> Toeplitz B-frags.
__global__ __launch_bounds__(256) void k_frag(const float* __restrict__ X,
                                              const float* __restrict__ kvec,
                                              unsigned int* __restrict__ Atab,
                                              unsigned int* __restrict__ Btab) {
  int bx = blockIdx.x;
  if (bx < 256) {
    int tid = bx * 256 + threadIdx.x;
    int lane = tid & 63;
    int f = tid >> 6;
    int bt = f >> 8, ut = f & 255;
    int row = bt * 16 + (lane & 15);
    int u0 = ut * 32 + ((lane >> 4) << 3);
    const float* xp = X + (size_t)row * L + u0;
    unsigned short v[8];
#pragma unroll
    for (int e = 0; e < 8; ++e) v[e] = f2bf(xp[e]);
    uint4v o;
    o.x = pack2(v[0], v[1]); o.y = pack2(v[2], v[3]);
    o.z = pack2(v[4], v[5]); o.w = pack2(v[6], v[7]);
    ((uint4v*)Atab)[(size_t)f * 64 + lane] = o;
  } else {
    int tid = (bx - 256) * 256 + threadIdx.x;
    int lane = tid & 63;
    int si = tid >> 6;
    int base = si * 16 + (lane & 15) - ((lane >> 4) << 3);
    unsigned short v[8];
#pragma unroll
    for (int e = 0; e < 8; ++e) {
      int idx = base - e;
      float x = (idx >= 0) ? kvec[idx] : 0.0f;
      v[e] = f2bf(x);
    }
    uint4v o;
    o.x = pack2(v[0], v[1]); o.y = pack2(v[2], v[3]);
    o.z = pack2(v[4], v[5]); o.w = pack2(v[6], v[7]);
    ((uint4v*)Btab)[(size_t)si * 64 + lane] = o;
  }
}

// Y = X * Toeplitz + D*X. One 16-wide t-tile per block, 4 waves = 4 batch tiles.
__global__ __launch_bounds__(256) void k_convmm(const short8* __restrict__ Atab,
                                                const short8* __restrict__ Btab,
                                                const float* __restrict__ X,
                                                const float* __restrict__ Dp,
                                                float* __restrict__ Y) {
  int tid = threadIdx.x, lane = tid & 63, bt = tid >> 6;
  int j = blockIdx.x;
  int nt = (j + 2) >> 1;
  f32x4 ae = {0.f, 0.f, 0.f, 0.f}, ao = {0.f, 0.f, 0.f, 0.f};
  const short8* Abase = Atab + (size_t)bt * 256 * 64 + lane;
  int ut = 0;
  for (; ut + 1 < nt; ut += 2) {
    short8 a0 = Abase[(size_t)ut * 64];
    short8 b0 = Btab[(size_t)(j - 2 * ut) * 64 + lane];
    ae = __builtin_amdgcn_mfma_f32_16x16x32_bf16(a0, b0, ae, 0, 0, 0);
    short8 a1 = Abase[(size_t)(ut + 1) * 64];
    short8 b1 = Btab[(size_t)(j - 2 * ut - 2) * 64 + lane];
    ao = __builtin_amdgcn_mfma_f32_16x16x32_bf16(a1, b1, ao, 0, 0, 0);
  }
  if (ut < nt) {
    short8 a0 = Abase[(size_t)ut * 64];
    short8 b0 = Btab[(size_t)(j - 2 * ut) * 64 + lane];
    ae = __builtin_amdgcn_mfma_f32_16x16x32_bf16(a0, b0, ae, 0, 0, 0);
  }
  float D0 = Dp[0];
  int t = j * 16 + (lane & 15);
#pragma unroll
  for (int r = 0; r < 4; ++r) {
    int b = bt * 16 + ((lane >> 4) << 2) + r;
    size_t o = (size_t)b * L + t;
    Y[o] = ae[r] + ao[r] + D0 * X[o];
  }
}

extern "C" void kernel_launch(void* const* d_in, const int* in_sizes, int n_in,
                              void* d_out, int out_size, void* d_ws, size_t ws_size,
                              hipStream_t stream) {
  const float* X  = (const float*)d_in[0];
  const float* A  = (const float*)d_in[1];
  const float* Bm = (const float*)d_in[2];
  const float* C  = (const float*)d_in[3];
  const float* D  = (const float*)d_in[4];
  const float* ld = (const float*)d_in[5];
  float* Y = (float*)d_out;

  float* ws = (float*)d_ws;
  float* kv = ws;                  // 8192
  float* V  = ws + 8192;           // 128*512
  float* W  = ws + 73728;          // 64*512
  float* B0 = ws + 106496;         // 512*512 (U scratch / ping)
  float* B1 = ws + 368640;         // 512*512 (pong)
  float* Xi = ws + 630784;         // 512*512 (A1inv)
  float* U  = B0;

  unsigned int* Atab = (unsigned int*)Xi;  // Xi dead after first k_sqv
  unsigned int* Btab = (unsigned int*)B1;  // B1 dead after 5th k_sqw

  k_diaginv<<<53, 256, 0, stream>>>(A, C, ld, Xi, W);
  // blocked triangular inversion: 32 -> 64 -> 128 -> 256 -> 512
  k_offmul<<<dim3(1, 1, 8), 256, 0, stream>>>(A + 32 * N, N, 64 * (N + 1),
                                              Xi, N, 64 * (N + 1),
                                              U, 32, 1024, ld, 0);
  k_offmul<<<dim3(1, 1, 8), 256, 0, stream>>>(Xi + 32 * (N + 1), N, 64 * (N + 1),
                                              U, 32, 1024,
                                              Xi + 32 * N, N, 64 * (N + 1), ld, 1);
  k_offmul<<<dim3(2, 2, 4), 256, 0, stream>>>(A + 64 * N, N, 128 * (N + 1),
                                              Xi, N, 128 * (N + 1),
                                              U, 64, 4096, ld, 0);
  k_offmul<<<dim3(2, 2, 4), 256, 0, stream>>>(Xi + 64 * (N + 1), N, 128 * (N + 1),
                                              U, 64, 4096,
                                              Xi + 64 * N, N, 128 * (N + 1), ld, 1);
  k_offmul<<<dim3(4, 4, 2), 256, 0, stream>>>(A + 128 * N, N, 256 * (N + 1),
                                              Xi, N, 256 * (N + 1),
                                              U, 128, 16384, ld, 0);
  k_offmul<<<dim3(4, 4, 2), 256, 0, stream>>>(Xi + 128 * (N + 1), N, 256 * (N + 1),
                                              U, 128, 16384,
                                              Xi + 128 * N, N, 256 * (N + 1), ld, 1);
  k_offmul<<<dim3(8, 8, 1), 256, 0, stream>>>(A + 256 * N, N, 0,
                                              Xi, N, 0,
                                              U, 256, 0, ld, 0);
  k_offmul<<<dim3(8, 8, 1), 256, 0, stream>>>(Xi + 256 * (N + 1), N, 0,
                                              U, 256, 0,
                                              Xi + 256 * N, N, 0, ld, 1);

  // squaring + Krylov doubling (Ad = 2*Xi - I folded into first squaring)
  k_sqv<<<65, 256, 0, stream>>>(Xi, B1, V, 1, 1, Bm, ld);    // B1 = Ad^2
  k_sqv<<<66, 256, 0, stream>>>(B1, B0, V, 2, 0, Bm, ld);    // B0 = Ad^4
  k_sqv<<<68, 256, 0, stream>>>(B0, B1, V, 4, 0, Bm, ld);    // B1 = Ad^8
  k_sqv<<<72, 256, 0, stream>>>(B1, B0, V, 8, 0, Bm, ld);    // B0 = Ad^16
  k_sqv<<<80, 256, 0, stream>>>(B0, B1, V, 16, 0, Bm, ld);   // B1 = Ad^32
  k_sqv<<<96, 256, 0, stream>>>(B1, B0, V, 32, 0, Bm, ld);   // B0 = Ad^64
  k_sqv<<<128, 256, 0, stream>>>(B0, B1, V, 64, 0, Bm, ld);  // B1 = Ad^128
  k_sqw<<<66, 256, 0, stream>>>(B1, B0, W, 1, 64);           // B0 = Ad^256
  k_sqw<<<68, 256, 0, stream>>>(B0, B1, W, 2, 64);           // B1 = Ad^512
  k_sqw<<<72, 256, 0, stream>>>(B1, B0, W, 4, 64);           // B0 = Ad^1024
  k_sqw<<<80, 256, 0, stream>>>(B0, B1, W, 8, 64);           // B1 = Ad^2048
  k_sqw<<<96, 256, 0, stream>>>(B1, B0, W, 16, 64);          // B0 = Ad^4096
  k_sqw<<<64, 256, 0, stream>>>(B0, (float*)nullptr, W, 32, 0);
  k_kfinal<<<64, 128, 0, stream>>>(W, V, kv);

  // Toeplitz conv via MFMA
  k_frag<<<384, 256, 0, stream>>>(X, kv, Atab, Btab);
  k_convmm<<<512, 256, 0, stream>>>((const short8*)Atab, (const short8*)Btab, X, D, Y);
}

// Round 5
// 490.473 us; speedup vs baseline: 2.2396x; 1.0821x over previous
//
#include <hip/hip_runtime.h>

#define N 512
#define L 8192

#define LOG_MIN -6.907755278982137f
#define LOG_MAX -2.302585092994046f

typedef __attribute__((ext_vector_type(8))) short short8;
typedef __attribute__((ext_vector_type(4))) float f32x4;
typedef __attribute__((ext_vector_type(4))) unsigned int uint4v;

__device__ __forceinline__ float get_delta(const float* logd) {
  float ld = logd[0];
  ld = fminf(fmaxf(ld, LOG_MIN), LOG_MAX);
  return expf(ld);
}
__device__ __forceinline__ unsigned short f2bf(float x) {
  union { float f; unsigned int u; } c; c.f = x;
  unsigned int u = c.u;
  u += 0x7FFFu + ((u >> 16) & 1u);
  return (unsigned short)(u >> 16);
}
__device__ __forceinline__ unsigned int pack2(unsigned short a, unsigned short b) {
  return (unsigned int)a | ((unsigned int)b << 16);
}

// ---------------------------------------------------------------------------
// ws layout (floats):
//   0       kvec (8192)        [64][128] row-major (q, r)
//   8192    Vt   (512*128)     Vt[n][r] = (Ad^r Bd)[n]   (col 0 = Bd)
//   73728   W    (64*512)      row 0 = C
//   106496  B0   (512*512)     U scratch early; squaring ping
//   368640  B1   (512*512)     squaring pong   -> Btab aliases
//   630784  Xi   (512*512)     A1^-1           -> Atab aliases
// ---------------------------------------------------------------------------

// Blocks 0-15: invert 32x32 diag blocks of A1 = I - h*A (wave-parallel subst).
// 16-43: zero strict-upper 64-tiles. 44-51: zero upper-right 32x32 of diag
// 64-tiles. 52: W[0] = C.
__global__ __launch_bounds__(256) void k_diaginv(const float* __restrict__ A,
                                                 const float* __restrict__ C,
                                                 const float* __restrict__ logd,
                                                 float* __restrict__ Xi,
                                                 float* __restrict__ W) {
  int b = blockIdx.x, tid = threadIdx.x;
  if (b < 16) {
    __shared__ float Ash[32][33];
    __shared__ float xs[32][33];
    __shared__ float dinv[32];
    float h = 0.5f * get_delta(logd);
    int i0 = b * 32;
    {
      int r = tid >> 3, c4 = (tid & 7) * 4;
      float4 v = *(const float4*)(A + (size_t)(i0 + r) * N + i0 + c4);
      Ash[r][c4] = v.x; Ash[r][c4 + 1] = v.y; Ash[r][c4 + 2] = v.z; Ash[r][c4 + 3] = v.w;
    }
    for (int i = tid; i < 32 * 33; i += 256) ((float*)xs)[i] = 0.f;
    __syncthreads();
    if (tid < 32) dinv[tid] = 1.f / (1.f - h * Ash[tid][tid]);
    __syncthreads();
    int t = tid >> 3, kl = tid & 7;
    for (int r = 0; r < 32; ++r) {
      float s = 0.f;
      for (int k = t + kl; k < r; k += 8) s += Ash[r][k] * xs[k][t];
      s += __shfl_xor(s, 1, 64);
      s += __shfl_xor(s, 2, 64);
      s += __shfl_xor(s, 4, 64);
      if (kl == 0 && t <= r)
        xs[r][t] = (((r == t) ? 1.f : 0.f) + h * s) * dinv[r];
      __syncthreads();
    }
    {
      int r = tid >> 3, c4 = (tid & 7) * 4;
      float4 v = {xs[r][c4], xs[r][c4 + 1], xs[r][c4 + 2], xs[r][c4 + 3]};
      *(float4*)(Xi + (size_t)(i0 + r) * N + i0 + c4) = v;
    }
    return;
  }
  if (b < 44) {
    int idx = b - 16, bi = 0, bj = 0, cnt = 0;
    for (int i = 0; i < 8; ++i)
      for (int j = i + 1; j < 8; ++j) { if (cnt == idx) { bi = i; bj = j; } ++cnt; }
    int r = tid >> 2, cq = (tid & 3) * 16;
    float4 z = {0.f, 0.f, 0.f, 0.f};
#pragma unroll
    for (int j = 0; j < 4; ++j)
      *(float4*)(Xi + (size_t)(bi * 64 + r) * N + bj * 64 + cq + 4 * j) = z;
    return;
  }
  if (b < 52) {
    int d = b - 44;
    int r = tid >> 3, c4 = (tid & 7) * 4;
    float4 z = {0.f, 0.f, 0.f, 0.f};
    *(float4*)(Xi + (size_t)(d * 64 + r) * N + d * 64 + 32 + c4) = z;
    return;
  }
  for (int i = tid; i < N; i += 256) W[i] = C[i];
}

// C_ = alpha * A_ * B_  (S x S x S, S = 32*gridDim.x), batched over blockIdx.z.
__global__ __launch_bounds__(256) void k_offmul(const float* __restrict__ Abase, int lda, int sA,
                                                const float* __restrict__ Bbase, int ldb, int sB,
                                                float* __restrict__ Cbase, int ldc, int sC,
                                                const float* __restrict__ logd, int amode) {
  int g = blockIdx.z;
  const float* A_ = Abase + (size_t)g * sA;
  const float* B_ = Bbase + (size_t)g * sB;
  float* C_ = Cbase + (size_t)g * sC;
  int S = gridDim.x * 32;
  int bi = blockIdx.y, bj = blockIdx.x;
  int tid = threadIdx.x;
  int tx = tid & 31, ty = tid >> 5;
  float alpha = (amode == 0) ? -0.5f * get_delta(logd) : -1.0f;
  __shared__ float As[32][33], Bs[32][33];
  float acc[4] = {0.f, 0.f, 0.f, 0.f};
  for (int kb = 0; kb < S; kb += 32) {
#pragma unroll
    for (int m = 0; m < 4; ++m) {
      As[ty + 8 * m][tx] = A_[(size_t)(bi * 32 + ty + 8 * m) * lda + kb + tx];
      Bs[ty + 8 * m][tx] = B_[(size_t)(kb + ty + 8 * m) * ldb + bj * 32 + tx];
    }
    __syncthreads();
#pragma unroll
    for (int kk = 0; kk < 32; ++kk) {
      float bv = Bs[kk][tx];
#pragma unroll
      for (int m = 0; m < 4; ++m) acc[m] += As[ty + 8 * m][kk] * bv;
    }
    __syncthreads();
  }
#pragma unroll
  for (int m = 0; m < 4; ++m)
    C_[(size_t)(bi * 32 + ty + 8 * m) * ldc + bj * 32 + tx] = alpha * acc[m];
}

// Bd: Vt[:,0] = delta * Xi * Bm.  128 blocks x 4 waves, one row per wave.
__global__ __launch_bounds__(256) void k_bd1(const float* __restrict__ Xi,
                                             const float* __restrict__ Bm,
                                             const float* __restrict__ logd,
                                             float* __restrict__ Vt) {
  __shared__ float bs[N];
  int tid = threadIdx.x;
  if (tid < 128) ((float4*)bs)[tid] = ((const float4*)Bm)[tid];
  __syncthreads();
  int w = tid >> 6, lane = tid & 63;
  int row = blockIdx.x * 4 + w;
  const float* Xr = Xi + (size_t)row * N + lane * 8;
  float4 a0 = *(const float4*)Xr;
  float4 a1 = *(const float4*)(Xr + 4);
  const float* bp = bs + lane * 8;
  float acc = a0.x * bp[0] + a0.y * bp[1] + a0.z * bp[2] + a0.w * bp[3]
            + a1.x * bp[4] + a1.y * bp[5] + a1.z * bp[6] + a1.w * bp[7];
  acc += __shfl_xor(acc, 1, 64);
  acc += __shfl_xor(acc, 2, 64);
  acc += __shfl_xor(acc, 4, 64);
  acc += __shfl_xor(acc, 8, 64);
  acc += __shfl_xor(acc, 16, 64);
  acc += __shfl_xor(acc, 32, 64);
  if (lane == 0) Vt[(size_t)row * 128] = get_delta(logd) * acc;
}

// 64x64-tile lower-tri squaring: Q = P*P (first: P := 2*Pin - I read-transform).
__device__ void sq64(const float* __restrict__ P, float* __restrict__ Q,
                     int bi, int bj, int tid, int first, float* sm) {
  if (bi < bj) {
    int r = tid >> 2, cq = (tid & 3) * 16;
    float4 z = {0.f, 0.f, 0.f, 0.f};
#pragma unroll
    for (int j = 0; j < 4; ++j)
      *(float4*)(Q + (size_t)(bi * 64 + r) * N + bj * 64 + cq + 4 * j) = z;
    return;
  }
  float* Ast = sm;            // [32][68]
  float* Bs = sm + 32 * 68;   // [32][64]
  int tx = tid & 15, ty = tid >> 4;
  float acc[4][4];
#pragma unroll
  for (int i = 0; i < 4; ++i)
#pragma unroll
    for (int j = 0; j < 4; ++j) acc[i][j] = 0.f;
  int ar = tid >> 2, aq = tid & 3;
  int bk = tid >> 3, bc = (tid & 7) * 8;
  for (int kb = bj * 64; kb < (bi + 1) * 64; kb += 32) {
    const float* asrc = P + (size_t)(bi * 64 + ar) * N + kb + aq * 8;
    float av[8];
    *(float4*)&av[0] = *(const float4*)asrc;
    *(float4*)&av[4] = *(const float4*)(asrc + 4);
    const float* bsrc = P + (size_t)(kb + bk) * N + bj * 64 + bc;
    float bv[8];
    *(float4*)&bv[0] = *(const float4*)bsrc;
    *(float4*)&bv[4] = *(const float4*)(bsrc + 4);
    if (first) {
      int gra = bi * 64 + ar, gca = kb + aq * 8;
      int grb = kb + bk, gcb = bj * 64 + bc;
#pragma unroll
      for (int j = 0; j < 8; ++j) {
        av[j] = 2.f * av[j] - ((gra == gca + j) ? 1.f : 0.f);
        bv[j] = 2.f * bv[j] - ((grb == gcb + j) ? 1.f : 0.f);
      }
    }
#pragma unroll
    for (int j = 0; j < 8; ++j) Ast[(aq * 8 + j) * 68 + ar] = av[j];
    *(float4*)&Bs[bk * 64 + bc] = *(float4*)&bv[0];
    *(float4*)&Bs[bk * 64 + bc + 4] = *(float4*)&bv[4];
    __syncthreads();
#pragma unroll 8
    for (int k = 0; k < 32; ++k) {
      float4 a = *(const float4*)&Ast[k * 68 + 4 * ty];
      float4 bb = *(const float4*)&Bs[k * 64 + 4 * tx];
      float ai[4] = {a.x, a.y, a.z, a.w};
      float bj4[4] = {bb.x, bb.y, bb.z, bb.w};
#pragma unroll
      for (int i = 0; i < 4; ++i)
#pragma unroll
        for (int j = 0; j < 4; ++j) acc[i][j] = fmaf(ai[i], bj4[j], acc[i][j]);
    }
    __syncthreads();
  }
#pragma unroll
  for (int i = 0; i < 4; ++i) {
    float4 v = {acc[i][0], acc[i][1], acc[i][2], acc[i][3]};
    *(float4*)(Q + (size_t)(bi * 64 + 4 * ty + i) * N + bj * 64 + 4 * tx) = v;
  }
}

// Blocks 0-63: squaring M -> Q. Blocks 64+: Vt[:, base+c] = (first?2P-I:P) * Vt[:,c]
// as a coalesced tiled GEMM (c masked to < base).
__global__ __launch_bounds__(256) void k_sqv(const float* __restrict__ P,
                                             float* __restrict__ Q,
                                             float* __restrict__ Vt,
                                             int base, int first,
                                             const float* __restrict__ logd) {
  __shared__ float sm[32 * 68 + 32 * 64];
  int bx = blockIdx.x, tid = threadIdx.x;
  if (bx < 64) { sq64(P, Q, bx >> 3, bx & 7, tid, first, sm); return; }
  int idx = bx - 64;
  int bi = idx & 15, cj = idx >> 4;
  float* As = sm;             // [32][33]
  float* Bs = sm + 32 * 33;   // [32][33]
  int tx = tid & 31, ty = tid >> 5;
  float acc[4] = {0.f, 0.f, 0.f, 0.f};
  int kmax = (bi + 1) * 32;   // P lower-triangular
  for (int kb = 0; kb < kmax; kb += 32) {
#pragma unroll
    for (int m = 0; m < 4; ++m) {
      int row = bi * 32 + ty + 8 * m;
      float a = P[(size_t)row * N + kb + tx];
      if (first) a = 2.f * a - ((row == kb + tx) ? 1.f : 0.f);
      As[(ty + 8 * m) * 33 + tx] = a;
      Bs[(ty + 8 * m) * 33 + tx] = Vt[(size_t)(kb + ty + 8 * m) * 128 + cj * 32 + tx];
    }
    __syncthreads();
#pragma unroll
    for (int kk = 0; kk < 32; ++kk) {
      float bv = Bs[kk * 33 + tx];
#pragma unroll
      for (int m = 0; m < 4; ++m) acc[m] += As[(ty + 8 * m) * 33 + kk] * bv;
    }
    __syncthreads();
  }
  int c = cj * 32 + tx;
  if (c < base) {
#pragma unroll
    for (int m = 0; m < 4; ++m)
      Vt[(size_t)(bi * 32 + ty + 8 * m) * 128 + base + c] = acc[m];
  }
}

// Blocks 0..nsq-1: squaring. Blocks nsq+: W[base+q][:] = W[q][:] * P as tiled GEMM.
__global__ __launch_bounds__(256) void k_sqw(const float* __restrict__ P,
                                             float* __restrict__ Q,
                                             float* __restrict__ W,
                                             int base, int nsq) {
  __shared__ float sm[32 * 68 + 32 * 64];
  int bx = blockIdx.x, tid = threadIdx.x;
  if (bx < nsq) { sq64(P, Q, bx >> 3, bx & 7, tid, 0, sm); return; }
  int cj = bx - nsq;          // column tile 0..15
  float* As = sm;             // [32][33]  As[q][k]
  float* Bs = sm + 32 * 33;   // [32][33]  Bs[k][c]
  int tx = tid & 31, ty = tid >> 5;
  float acc[4] = {0.f, 0.f, 0.f, 0.f};
  for (int kb = 0; kb < N; kb += 32) {
#pragma unroll
    for (int m = 0; m < 4; ++m) {
      As[(ty + 8 * m) * 33 + tx] = W[(size_t)(ty + 8 * m) * N + kb + tx];
      Bs[(ty + 8 * m) * 33 + tx] = P[(size_t)(kb + ty + 8 * m) * N + cj * 32 + tx];
    }
    __syncthreads();
#pragma unroll
    for (int kk = 0; kk < 32; ++kk) {
      float bv = Bs[kk * 33 + tx];
#pragma unroll
      for (int m = 0; m < 4; ++m) acc[m] += As[(ty + 8 * m) * 33 + kk] * bv;
    }
    __syncthreads();
  }
#pragma unroll
  for (int m = 0; m < 4; ++m) {
    int q = ty + 8 * m;
    if (q < base)
      W[(size_t)(base + q) * N + cj * 32 + tx] = acc[m];
  }
}

// kvec[64][128] = W(64x512) * Vt(512x128). Grid (4,2) of 32x32 tiles.
__global__ __launch_bounds__(256) void k_kfinal(const float* __restrict__ W,
                                                const float* __restrict__ Vt,
                                                float* __restrict__ kvec) {
  __shared__ float As[32][33], Bs[32][33];
  int bi = blockIdx.y, bj = blockIdx.x;
  int tid = threadIdx.x;
  int tx = tid & 31, ty = tid >> 5;
  float acc[4] = {0.f, 0.f, 0.f, 0.f};
  for (int kb = 0; kb < N; kb += 32) {
#pragma unroll
    for (int m = 0; m < 4; ++m) {
      As[ty + 8 * m][tx] = W[(size_t)(bi * 32 + ty + 8 * m) * N + kb + tx];
      Bs[ty + 8 * m][tx] = Vt[(size_t)(kb + ty + 8 * m) * 128 + bj * 32 + tx];
    }
    __syncthreads();
#pragma unroll
    for (int kk = 0; kk < 32; ++kk) {
      float bv = Bs[kk][tx];
#pragma unroll
      for (int m = 0; m < 4; ++m) acc[m] += As[ty + 8 * m][kk] * bv;
    }
    __syncthreads();
  }
#pragma unroll
  for (int m = 0; m < 4; ++m)
    kvec[(size_t)(bi * 32 + ty + 8 * m) * 128 + bj * 32 + tx] = acc[m];
}

// Fused: blocks 0-255 -> X A-frags; blocks 256-383 -> Toeplitz B-frags.
__global__ __launch_bounds__(256) void k_frag(const float* __restrict__ X,
                                              const float* __restrict__ kvec,
                                              unsigned int* __restrict__ Atab,
                                              unsigned int* __restrict__ Btab) {
  int bx = blockIdx.x;
  if (bx < 256) {
    int tid = bx * 256 + threadIdx.x;
    int lane = tid & 63;
    int f = tid >> 6;
    int bt = f >> 8, ut = f & 255;
    int row = bt * 16 + (lane & 15);
    int u0 = ut * 32 + ((lane >> 4) << 3);
    const float* xp = X + (size_t)row * L + u0;
    unsigned short v[8];
#pragma unroll
    for (int e = 0; e < 8; ++e) v[e] = f2bf(xp[e]);
    uint4v o;
    o.x = pack2(v[0], v[1]); o.y = pack2(v[2], v[3]);
    o.z = pack2(v[4], v[5]); o.w = pack2(v[6], v[7]);
    ((uint4v*)Atab)[(size_t)f * 64 + lane] = o;
  } else {
    int tid = (bx - 256) * 256 + threadIdx.x;
    int lane = tid & 63;
    int si = tid >> 6;
    int base = si * 16 + (lane & 15) - ((lane >> 4) << 3);
    unsigned short v[8];
#pragma unroll
    for (int e = 0; e < 8; ++e) {
      int idx = base - e;
      float x = (idx >= 0) ? kvec[idx] : 0.0f;
      v[e] = f2bf(x);
    }
    uint4v o;
    o.x = pack2(v[0], v[1]); o.y = pack2(v[2], v[3]);
    o.z = pack2(v[4], v[5]); o.w = pack2(v[6], v[7]);
    ((uint4v*)Btab)[(size_t)si * 64 + lane] = o;
  }
}

// Y = X * Toeplitz + D*X. One 16-wide t-tile per block, 4 waves = 4 batch tiles.
__global__ __launch_bounds__(256) void k_convmm(const short8* __restrict__ Atab,
                                                const short8* __restrict__ Btab,
                                                const float* __restrict__ X,
                                                const float* __restrict__ Dp,
                                                float* __restrict__ Y) {
  int tid = threadIdx.x, lane = tid & 63, bt = tid >> 6;
  int j = blockIdx.x;
  int nt = (j + 2) >> 1;
  f32x4 ae = {0.f, 0.f, 0.f, 0.f}, ao = {0.f, 0.f, 0.f, 0.f};
  const short8* Abase = Atab + (size_t)bt * 256 * 64 + lane;
  int ut = 0;
  for (; ut + 1 < nt; ut += 2) {
    short8 a0 = Abase[(size_t)ut * 64];
    short8 b0 = Btab[(size_t)(j - 2 * ut) * 64 + lane];
    ae = __builtin_amdgcn_mfma_f32_16x16x32_bf16(a0, b0, ae, 0, 0, 0);
    short8 a1 = Abase[(size_t)(ut + 1) * 64];
    short8 b1 = Btab[(size_t)(j - 2 * ut - 2) * 64 + lane];
    ao = __builtin_amdgcn_mfma_f32_16x16x32_bf16(a1, b1, ao, 0, 0, 0);
  }
  if (ut < nt) {
    short8 a0 = Abase[(size_t)ut * 64];
    short8 b0 = Btab[(size_t)(j - 2 * ut) * 64 + lane];
    ae = __builtin_amdgcn_mfma_f32_16x16x32_bf16(a0, b0, ae, 0, 0, 0);
  }
  float D0 = Dp[0];
  int t = j * 16 + (lane & 15);
#pragma unroll
  for (int r = 0; r < 4; ++r) {
    int b = bt * 16 + ((lane >> 4) << 2) + r;
    size_t o = (size_t)b * L + t;
    Y[o] = ae[r] + ao[r] + D0 * X[o];
  }
}

extern "C" void kernel_launch(void* const* d_in, const int* in_sizes, int n_in,
                              void* d_out, int out_size, void* d_ws, size_t ws_size,
                              hipStream_t stream) {
  const float* X  = (const float*)d_in[0];
  const float* A  = (const float*)d_in[1];
  const float* Bm = (const float*)d_in[2];
  const float* C  = (const float*)d_in[3];
  const float* D  = (const float*)d_in[4];
  const float* ld = (const float*)d_in[5];
  float* Y = (float*)d_out;

  float* ws = (float*)d_ws;
  float* kv = ws;                  // 8192
  float* Vt = ws + 8192;           // 512*128
  float* W  = ws + 73728;          // 64*512
  float* B0 = ws + 106496;         // 512*512 (U scratch / ping)
  float* B1 = ws + 368640;         // 512*512 (pong)
  float* Xi = ws + 630784;         // 512*512 (A1inv)
  float* U  = B0;

  unsigned int* Atab = (unsigned int*)Xi;  // Xi dead after first k_sqv
  unsigned int* Btab = (unsigned int*)B1;  // B1 dead after 5th k_sqw

  k_diaginv<<<53, 256, 0, stream>>>(A, C, ld, Xi, W);
  // blocked triangular inversion: 32 -> 64 -> 128 -> 256 -> 512
  k_offmul<<<dim3(1, 1, 8), 256, 0, stream>>>(A + 32 * N, N, 64 * (N + 1),
                                              Xi, N, 64 * (N + 1),
                                              U, 32, 1024, ld, 0);
  k_offmul<<<dim3(1, 1, 8), 256, 0, stream>>>(Xi + 32 * (N + 1), N, 64 * (N + 1),
                                              U, 32, 1024,
                                              Xi + 32 * N, N, 64 * (N + 1), ld, 1);
  k_offmul<<<dim3(2, 2, 4), 256, 0, stream>>>(A + 64 * N, N, 128 * (N + 1),
                                              Xi, N, 128 * (N + 1),
                                              U, 64, 4096, ld, 0);
  k_offmul<<<dim3(2, 2, 4), 256, 0, stream>>>(Xi + 64 * (N + 1), N, 128 * (N + 1),
                                              U, 64, 4096,
                                              Xi + 64 * N, N, 128 * (N + 1), ld, 1);
  k_offmul<<<dim3(4, 4, 2), 256, 0, stream>>>(A + 128 * N, N, 256 * (N + 1),
                                              Xi, N, 256 * (N + 1),
                                              U, 128, 16384, ld, 0);
  k_offmul<<<dim3(4, 4, 2), 256, 0, stream>>>(Xi + 128 * (N + 1), N, 256 * (N + 1),
                                              U, 128, 16384,
                                              Xi + 128 * N, N, 256 * (N + 1), ld, 1);
  k_offmul<<<dim3(8, 8, 1), 256, 0, stream>>>(A + 256 * N, N, 0,
                                              Xi, N, 0,
                                              U, 256, 0, ld, 0);
  k_offmul<<<dim3(8, 8, 1), 256, 0, stream>>>(Xi + 256 * (N + 1), N, 0,
                                              U, 256, 0,
                                              Xi + 256 * N, N, 0, ld, 1);

  // Bd, then fused squaring + Krylov doubling (Ad = 2*Xi - I via read-transform)
  k_bd1<<<128, 256, 0, stream>>>(Xi, Bm, ld, Vt);
  k_sqv<<<80, 256, 0, stream>>>(Xi, B1, Vt, 1, 1, ld);   // B1 = Ad^2
  k_sqv<<<80, 256, 0, stream>>>(B1, B0, Vt, 2, 0, ld);   // B0 = Ad^4
  k_sqv<<<80, 256, 0, stream>>>(B0, B1, Vt, 4, 0, ld);   // B1 = Ad^8
  k_sqv<<<80, 256, 0, stream>>>(B1, B0, Vt, 8, 0, ld);   // B0 = Ad^16
  k_sqv<<<80, 256, 0, stream>>>(B0, B1, Vt, 16, 0, ld);  // B1 = Ad^32
  k_sqv<<<80, 256, 0, stream>>>(B1, B0, Vt, 32, 0, ld);  // B0 = Ad^64
  k_sqv<<<96, 256, 0, stream>>>(B0, B1, Vt, 64, 0, ld);  // B1 = Ad^128
  k_sqw<<<80, 256, 0, stream>>>(B1, B0, W, 1, 64);       // B0 = Ad^256
  k_sqw<<<80, 256, 0, stream>>>(B0, B1, W, 2, 64);       // B1 = Ad^512
  k_sqw<<<80, 256, 0, stream>>>(B1, B0, W, 4, 64);       // B0 = Ad^1024
  k_sqw<<<80, 256, 0, stream>>>(B0, B1, W, 8, 64);       // B1 = Ad^2048
  k_sqw<<<80, 256, 0, stream>>>(B1, B0, W, 16, 64);      // B0 = Ad^4096
  k_sqw<<<16, 256, 0, stream>>>(B0, (float*)nullptr, W, 32, 0);
  k_kfinal<<<dim3(4, 2), 256, 0, stream>>>(W, Vt, kv);

  // Toeplitz conv via MFMA
  k_frag<<<384, 256, 0, stream>>>(X, kv, Atab, Btab);
  k_convmm<<<512, 256, 0, stream>>>((const short8*)Atab, (const short8*)Btab, X, D, Y);
}